// Round 7
// baseline (139.819 us; speedup 1.0000x reference)
//
#include <hip/hip_runtime.h>

typedef __attribute__((ext_vector_type(4))) float f32x4;
typedef __attribute__((ext_vector_type(8))) short bf16x8;

__device__ __forceinline__ short f2bf(float f) {
    union { float f; unsigned u; } v; v.f = f;
    unsigned u = v.u + 0x7FFFu + ((v.u >> 16) & 1u);   // RNE
    return (short)(u >> 16);
}
__device__ __forceinline__ int pack_bf2(float a, float b) {
    union { float f; unsigned u; } ua, ub; ua.f = a; ub.f = b;
    unsigned x = ua.u + 0x8000u, y = ub.u + 0x8000u;   // round half-up
    return (int)__builtin_amdgcn_perm(y, x, 0x07060302u);
}
__device__ __forceinline__ float bflo(int p) {
    union { int i; float f; } v; v.i = p << 16; return v.f;
}
__device__ __forceinline__ float bfhi(int p) {
    union { int i; float f; } v; v.i = p & 0xffff0000; return v.f;
}

// ---------------------------------------------------------------------------
// Prep (16 blocks x 256) — R4-verified outputs:
//  AbP16: per c, frag f=(rt*2+kc)*64+L holds A_c[pi(rt*16+(L&15))][32kc+8(L>>4)+j]
//  Bb16 : bias GEMV A-op, rows=comps: -2*(A_c m_c)[32kc+8q+j]
//  kscal: m^T A m
// ---------------------------------------------------------------------------
__global__ void gmm_prep(const float* __restrict__ Ainv,
                         const float* __restrict__ means,
                         short* __restrict__ AbP16,
                         short* __restrict__ Bb16,
                         float* __restrict__ kscal) {
    __shared__ float sA[64 * 68];
    __shared__ float sm[64];
    __shared__ float sb[64];
    const int c = blockIdx.x, t = threadIdx.x;
    const float* A = Ainv + c * 4096;
    #pragma unroll
    for (int i = 0; i < 4; ++i) {
        int flat = i * 1024 + t * 4;
        int r = flat >> 6, col = flat & 63;
        *(f32x4*)&sA[r * 68 + col] = *(const f32x4*)(A + flat);
    }
    if (t < 64) sm[t] = means[c * 64 + t];
    __syncthreads();
    {   // b[j] = A[j,:].m  (4 lanes per row)
        int j = t >> 2, seg = t & 3;
        float p = 0.f;
        #pragma unroll
        for (int k = 0; k < 16; ++k) p += sA[j * 68 + seg * 16 + k] * sm[seg * 16 + k];
        p += __shfl_xor(p, 1, 64); p += __shfl_xor(p, 2, 64);
        if ((t & 3) == 0) sb[j] = p;
    }
    __syncthreads();
    if (t < 64) {
        float km = sm[t] * sb[t];
        #pragma unroll
        for (int off = 32; off >= 1; off >>= 1) km += __shfl_xor(km, off, 64);
        if (t == 0) kscal[c] = km;
    }
    #pragma unroll
    for (int rep = 0; rep < 2; ++rep) {     // permuted A fragments
        int f = rep * 256 + t;
        int rt = f >> 7, kc = (f >> 6) & 1, L = f & 63;
        int ln = L & 15, q = L >> 4;
        int pj = (rt >> 1) * 32 + 8 * (ln >> 2) + 4 * (rt & 1) + (ln & 3);
        const float* src = &sA[pj * 68 + 32 * kc + 8 * q];
        bf16x8 v;
        #pragma unroll
        for (int j = 0; j < 8; ++j) v[j] = f2bf(src[j]);
        *(bf16x8*)(AbP16 + c * 4096 + f * 8) = v;
    }
    if (t < 8) {                            // bias GEMV frags (row = comp c)
        int kc = t >> 2, q = t & 3, L = q * 16 + c;
        bf16x8 v;
        #pragma unroll
        for (int j = 0; j < 8; ++j) v[j] = f2bf(-2.f * sb[32 * kc + 8 * q + j]);
        *(bf16x8*)(Bb16 + kc * 512 + L * 8) = v;
    }
}

union BFrag { bf16x8 v; int i[4]; };

// stage one 32 KB comp-group into LDS; layout is exactly wave-uniform base +
// lane*16, so use direct global->LDS DMA when available (no VGPR round-trip,
// no ds_write pipe cost).
__device__ __forceinline__ void stage_group(short* dstLds, const short* srcG, int tid) {
#if __has_builtin(__builtin_amdgcn_global_load_lds)
    const int lane = tid & 63, w = tid >> 6;
    const int4* src = (const int4*)srcG;
    int4* dst = (int4*)dstLds;
    #pragma unroll
    for (int i = 0; i < 8; ++i) {
        int bidx = i * 256 + w * 64;        // int4 index, wave-uniform
        __builtin_amdgcn_global_load_lds(
            (const __attribute__((address_space(1))) unsigned int*)(src + bidx + lane),
            (__attribute__((address_space(3))) unsigned int*)(dst + bidx),
            16, 0, 0);
    }
#else
    #pragma unroll
    for (int i = 0; i < 8; ++i)
        ((int4*)dstLds)[i * 256 + tid] = ((const int4*)srcG)[i * 256 + tid];
#endif
}

// ---------------------------------------------------------------------------
// Main (1024 blocks x 256): R6 skeleton; per-comp MFMA C-init = 0 (no LDS
// dependency); linear+const via per-tile GEMV (kscal in C-init); owner-quad
// (q==g) log accumulation; group order rotated per block.
// ---------------------------------------------------------------------------
__global__ __launch_bounds__(256) void gmm_main(
    const float* __restrict__ X,
    const float* __restrict__ weights,
    const short* __restrict__ AbP16,
    const short* __restrict__ Bb16,
    const float* __restrict__ kscal,
    float* __restrict__ out) {

    __shared__ short sAb[16384];          // 32 KB: 4 comps x 8 KB
    __shared__ float sW[16];

    const int tid = threadIdx.x;
    const int lane = tid & 63, w = tid >> 6;
    const int q = lane >> 4, ln = lane & 15;
    const int base = blockIdx.x * 256 + w * 64;
    const int boff = blockIdx.x & 3;
    const f32x4 zero4 = {0.f, 0.f, 0.f, 0.f};

    stage_group(sAb, AbP16 + boff * 16384, tid);
    if (tid < 16) sW[tid] = weights[tid];

    // x -> persistent packed bf16 B-frags
    BFrag xb[4][2];
    #pragma unroll
    for (int t = 0; t < 4; ++t) {
        const float* xr = X + (size_t)(base + t * 16 + ln) * 64 + 8 * q;
        #pragma unroll
        for (int kc = 0; kc < 2; ++kc) {
            f32x4 a = *(const f32x4*)(xr + 32 * kc);
            f32x4 b = *(const f32x4*)(xr + 32 * kc + 4);
            xb[t][kc].i[0] = pack_bf2(a[0], a[1]);
            xb[t][kc].i[1] = pack_bf2(a[2], a[3]);
            xb[t][kc].i[2] = pack_bf2(b[0], b[1]);
            xb[t][kc].i[3] = pack_bf2(b[2], b[3]);
        }
    }

    // lin[t][r] = kscal[4q+r] - 2 b_{4q+r}.x_n  (per-tile GEMV, R4-verified)
    f32x4 kw  = *(const f32x4*)(kscal + 4 * q);
    bf16x8 bb0 = *(const bf16x8*)(Bb16 + lane * 8);
    bf16x8 bb1 = *(const bf16x8*)(Bb16 + 512 + lane * 8);
    f32x4 lin[4];
    #pragma unroll
    for (int t = 0; t < 4; ++t) {
        lin[t] = __builtin_amdgcn_mfma_f32_16x16x32_bf16(bb0, xb[t][0].v, kw, 0, 0, 0);
        lin[t] = __builtin_amdgcn_mfma_f32_16x16x32_bf16(bb1, xb[t][1].v, lin[t], 0, 0, 0);
    }

    __syncthreads();                      // drains stage-0 DMA too

    float slog[4] = {0.f, 0.f, 0.f, 0.f};

    #pragma unroll 1
    for (int gi = 0; gi < 4; ++gi) {
        const int g = (gi + boff) & 3;
        #pragma unroll 1
        for (int cl = 0; cl < 4; ++cl) {
            bf16x8 af[8];
            #pragma unroll
            for (int f = 0; f < 8; ++f)
                af[f] = *(const bf16x8*)&sAb[cl * 4096 + f * 512 + lane * 8];
            const float wcc = sW[g * 4 + cl];

            #pragma unroll
            for (int t = 0; t < 4; ++t) {
                float dp = 0.f;
                #pragma unroll
                for (int rt = 0; rt < 4; ++rt) {
                    f32x4 acc = __builtin_amdgcn_mfma_f32_16x16x32_bf16(
                        af[rt * 2 + 0], xb[t][0].v, zero4, 0, 0, 0);
                    acc = __builtin_amdgcn_mfma_f32_16x16x32_bf16(
                        af[rt * 2 + 1], xb[t][1].v, acc, 0, 0, 0);
                    int pa = xb[t][rt >> 1].i[(rt & 1) * 2];
                    int pb = xb[t][rt >> 1].i[(rt & 1) * 2 + 1];
                    dp += acc[0] * bflo(pa) + acc[1] * bfhi(pa)
                        + acc[2] * bflo(pb) + acc[3] * bfhi(pb);
                }
                dp += __shfl_xor(dp, 16, 64);
                dp += __shfl_xor(dp, 32, 64);
                float linv = cl == 0 ? lin[t][0] : cl == 1 ? lin[t][1]
                           : cl == 2 ? lin[t][2] : lin[t][3];
                if (q == g) {             // owner quad accumulates its group
                    float d = fmaxf(dp + linv, 1e-30f);
                    slog[t] = fmaf(wcc, __builtin_amdgcn_logf(d), slog[t]);
                }
            }
        }
        if (gi < 3) {                     // restage next group (rotated order)
            __syncthreads();
            stage_group(sAb, AbP16 + ((gi + 1 + boff) & 3) * 16384, tid);
            __syncthreads();
        }
    }

    // combine the 4 quads' group-partials, write
    #pragma unroll
    for (int t = 0; t < 4; ++t) {
        float tot = slog[t];
        tot += __shfl_xor(tot, 16, 64);
        tot += __shfl_xor(tot, 32, 64);
        if (q == 0) out[base + t * 16 + ln] = __builtin_amdgcn_exp2f(tot);
    }
}

extern "C" void kernel_launch(void* const* d_in, const int* in_sizes, int n_in,
                              void* d_out, int out_size, void* d_ws, size_t ws_size,
                              hipStream_t stream) {
    const float* X       = (const float*)d_in[0];
    const float* Ainv    = (const float*)d_in[1];
    const float* means   = (const float*)d_in[2];
    const float* weights = (const float*)d_in[3];
    float* out = (float*)d_out;
    const int N = in_sizes[0] / 64;

    short* AbP16 = (short*)d_ws;                       // 131072 B
    short* Bb16  = (short*)((char*)d_ws + 131072);     // 2048 B
    float* kscal = (float*)((char*)d_ws + 133120);     // 64 B

    gmm_prep<<<dim3(16), dim3(256), 0, stream>>>(Ainv, means, AbP16, Bb16, kscal);
    gmm_main<<<dim3(N / 256), dim3(256), 0, stream>>>(X, weights, AbP16, Bb16, kscal, out);
}